// Round 7
// baseline (468.744 us; speedup 1.0000x reference)
//
#include <hip/hip_runtime.h>
#include <hip/hip_bf16.h>
#include <cstdint>
#include <cstddef>

#define N_NODES 50000
#define N_EDGES 800000
#define IN_CH 64
#define HID_CH 128
#define N_GRAPHS 64

typedef short s16x8 __attribute__((ext_vector_type(8)));
typedef float f32x4 __attribute__((ext_vector_type(4)));

__device__ __forceinline__ float bf2f(__hip_bfloat16 v) { return __bfloat162float(v); }
__device__ __forceinline__ float bfbits2f(unsigned hs) {
  union { unsigned u; float f; } v; v.u = hs << 16; return v.f;
}
__device__ __forceinline__ float bfhi2f(unsigned w) {
  union { unsigned u; float f; } v; v.u = w & 0xffff0000u; return v.f;
}
__device__ __forceinline__ short f2bfs(float f) {
  __hip_bfloat16 h = __float2bfloat16(f); return *(short*)&h;
}
__device__ __forceinline__ unsigned short f2bfu(float f) {
  __hip_bfloat16 h = __float2bfloat16(f); return *(unsigned short*)&h;
}

#if __has_builtin(__builtin_amdgcn_exp2f)
__device__ __forceinline__ float fast_exp2(float x) { return __builtin_amdgcn_exp2f(x); }
#else
__device__ __forceinline__ float fast_exp2(float x) { return exp2f(x); }
#endif

// add value from quad-lane xor 1 then xor 2 (quad_perm DPP, no LDS)
__device__ __forceinline__ float quad_reduce_add(float d) {
#if __has_builtin(__builtin_amdgcn_mov_dpp)
  union { float f; int i; } u, r;
  u.f = d;
  r.i = __builtin_amdgcn_mov_dpp(u.i, 0xB1, 0xF, 0xF, true);  // quad_perm [1,0,3,2]
  d += r.f;
  u.f = d;
  r.i = __builtin_amdgcn_mov_dpp(u.i, 0x4E, 0xF, 0xF, true);  // quad_perm [2,3,0,1]
  d += r.f;
  return d;
#else
  d += __shfl_xor(d, 1, 64);
  d += __shfl_xor(d, 2, 64);
  return d;
#endif
}

// flags[0]: 1 if float tensors are fp32, 0 if bf16
// flags[1]: 1 if int tensors are int64, 0 if int32

__device__ __forceinline__ float load_f(const void* p, int i, int fp32) {
  return fp32 ? ((const float*)p)[i] : bf2f(((const __hip_bfloat16*)p)[i]);
}
__device__ __forceinline__ int load_id_clamped(const void* p, int i, int i64, int limit) {
  long long v = i64 ? ((const long long*)p)[i] : (long long)((const int*)p)[i];
  if (v < 0) v = 0;
  if (v >= limit) v = limit - 1;
  return (int)v;
}
__device__ __forceinline__ long long load_b(const void* p, int i, int i64) {
  return i64 ? ((const long long*)p)[i] : (long long)((const int*)p)[i];
}

#define NB_SCAN ((N_NODES + 255) / 256)   // 196

// ---------------- fused detect + init ----------------
// blocks 0..NB_SCAN-1: zero cnt/tmp/pooled.  block NB_SCAN: dtype detection.

__global__ void detect_init(const unsigned* __restrict__ xr,
                            const unsigned* __restrict__ eir,
                            int* __restrict__ flags,
                            int* cnt, int* tmp, float* pooled) {
  if (blockIdx.x == NB_SCAN) {
    __shared__ int cnt_plaus, cnt_odd_nz;
    if (threadIdx.x == 0) { cnt_plaus = 0; cnt_odd_nz = 0; }
    __syncthreads();
    int t = threadIdx.x;
    {
      unsigned h = xr[t] & 0xffffu;
      unsigned e = (h >> 7) & 0xffu;
      if (e == 0u || (e >= 90u && e <= 150u)) atomicAdd(&cnt_plaus, 1);
    }
    if (eir[2 * t + 1] != 0u) atomicAdd(&cnt_odd_nz, 1);
    __syncthreads();
    if (t == 0) {
      flags[0] = (cnt_plaus < 160) ? 1 : 0;
      flags[1] = (cnt_odd_nz == 0) ? 1 : 0;
    }
    return;
  }
  int i = blockIdx.x * 256 + threadIdx.x;
  if (i < N_NODES) { cnt[i] = 0; tmp[i] = 0; }
  if (i < N_GRAPHS * HID_CH) pooled[i] = 0.f;
}

// ---------------- weight canonicalization ----------------
// W logical [KD][128] -> image WT[((k>>3)*128 + c)*8 + (k&7)]  ([k/8][col][8])
// B-fragment for (kt,quad,col) is then the contiguous 16B at ((kt*4+quad)*128+col)*8.

__global__ void conv_wt(const void* s0, const void* s1, const void* s2, const void* s3,
                        const void* s4, const void* s5, const void* s6, const void* s7,
                        __hip_bfloat16* d0, __hip_bfloat16* d1, __hip_bfloat16* d2, __hip_bfloat16* d3,
                        __hip_bfloat16* d4, __hip_bfloat16* d5, __hip_bfloat16* d6, __hip_bfloat16* d7,
                        const int* __restrict__ flags) {
  const void* S[8] = {s0, s1, s2, s3, s4, s5, s6, s7};
  __hip_bfloat16* D[8] = {d0, d1, d2, d3, d4, d5, d6, d7};
  int i = blockIdx.x * blockDim.x + threadIdx.x;
  int f = flags[0];
  if (i >= 4 * 64 * 128 + 4 * 128 * 128) return;
  int m, r;
  if (i < 4 * 64 * 128) { m = i >> 13; r = i & 8191; }
  else { int j = i - 4 * 64 * 128; m = 4 + (j >> 14); r = j & 16383; }
  int k = r >> 7, c = r & 127;
  D[m][(((k >> 3) * 128 + c) << 3) + (k & 7)] = __float2bfloat16(load_f(S[m], r, f));
}

// ---------------- CSR build ----------------

__global__ void count_deg(const void* __restrict__ ei, int* __restrict__ cnt,
                          const int* __restrict__ flags) {
  int e = blockIdx.x * blockDim.x + threadIdx.x;
  int f = flags[1];
  if (e < N_EDGES) atomicAdd(&cnt[load_id_clamped(ei, N_EDGES + e, f, N_NODES)], 1);
}

__global__ __launch_bounds__(256)
void scan1(const int* __restrict__ cnt, int* __restrict__ offs, int* __restrict__ bsum) {
  __shared__ int wsum[4];
  int t = threadIdx.x, lane = t & 63, w = t >> 6;
  int i = blockIdx.x * 256 + t;
  int v = (i < N_NODES) ? cnt[i] : 0;
  int x = v;
  #pragma unroll
  for (int o = 1; o < 64; o <<= 1) { int y = __shfl_up(x, o, 64); if (lane >= o) x += y; }
  if (lane == 63) wsum[w] = x;
  __syncthreads();
  if (t == 0) {
    int run = 0;
    #pragma unroll
    for (int k = 0; k < 4; ++k) { int tv = wsum[k]; wsum[k] = run; run += tv; }
    bsum[blockIdx.x] = run;
  }
  __syncthreads();
  if (i < N_NODES) offs[i] = wsum[w] + x - v;
}

__global__ __launch_bounds__(256)
void scan2(int* __restrict__ bsum, int* __restrict__ offs) {
  __shared__ int wsum[4];
  int t = threadIdx.x, lane = t & 63, w = t >> 6;
  int v = (t < NB_SCAN) ? bsum[t] : 0;
  int x = v;
  #pragma unroll
  for (int o = 1; o < 64; o <<= 1) { int y = __shfl_up(x, o, 64); if (lane >= o) x += y; }
  if (lane == 63) wsum[w] = x;
  __syncthreads();
  if (t == 0) {
    int run = 0;
    #pragma unroll
    for (int k = 0; k < 4; ++k) { int tv = wsum[k]; wsum[k] = run; run += tv; }
    offs[N_NODES] = run;
  }
  __syncthreads();
  if (t < NB_SCAN) bsum[t] = wsum[w] + x - v;
}

__global__ void scan3(int* __restrict__ offs, const int* __restrict__ bsum) {
  int i = blockIdx.x * blockDim.x + threadIdx.x;
  if (i < N_NODES) offs[i] += bsum[i >> 8];
}

__global__ void scatter_edges(const void* __restrict__ ei, const int* __restrict__ offs,
                              int* __restrict__ tmp, int* __restrict__ ssrc,
                              const int* __restrict__ flags) {
  int e = blockIdx.x * blockDim.x + threadIdx.x;
  int f = flags[1];
  if (e < N_EDGES) {
    int src = load_id_clamped(ei, e, f, N_NODES);
    int dst = load_id_clamped(ei, N_EDGES + e, f, N_NODES);
    int pos = offs[dst] + atomicAdd(&tmp[dst], 1);
    ssrc[pos] = src;
  }
}

// ---------------- GEMM v3: B-in-registers, no LDS, no barriers ----------------
// Grid: (row-chunks of 256, nmats*2). mat = moff + (by>>1), ch = by&1.
// Wave owns 64 consecutive rows (4 row-tiles) and 64 cols (its col-half).
// B panel: 16 (KD=128) / 8 (KD=64) register fragments, loaded once from the
// L2-hot weight image. Per row-tile: load A-frags -> KT*4 MFMAs -> store.
// Outputs: Q -> Qo [row*128], K -> KV [row*256], V -> KV [row*256+128], S -> So [row*128].
// In-place safety (X == So): each row is read (into regs) and written only by
// the same wave, reads precede writes; launch S as its own dispatch when X aliases.

template<int KD>
__global__ __launch_bounds__(256)
void gemm_v3(const void* X,
             const short* __restrict__ w0, const short* __restrict__ w1,
             const short* __restrict__ w2, const short* __restrict__ w3,
             const void* __restrict__ b0, const void* __restrict__ b1,
             const void* __restrict__ b2, const void* __restrict__ b3,
             short* Qo, short* KVo, short* So,
             const int* __restrict__ flags, int xf_is_flag, int moff, int n)
{
  constexpr int KT = KD / 32;
  const int f  = flags[0];
  const int xf = xf_is_flag ? f : 0;
  const int mat = moff + (blockIdx.y >> 1);
  const int ch  = blockIdx.y & 1;
  const int wid  = threadIdx.x >> 6;
  const int lane = threadIdx.x & 63;
  const int quad = lane >> 4;
  const int mm   = lane & 15;

  const short* wts[4] = {w0, w1, w2, w3};
  const void* bias[4] = {b0, b1, b2, b3};
  short* obase[4] = {Qo, KVo, KVo, So};
  const int ostr[4] = {128, 256, 256, 128};
  const int ooff[4] = {0, 0, 128, 0};

  const short* WT = wts[mat];
  short* O = obase[mat];
  const int os = ostr[mat];
  const int oo = ooff[mat];

  // B panel in registers
  s16x8 bfrag[KT][4];
  float bv[4];
  #pragma unroll
  for (int c4 = 0; c4 < 4; ++c4) {
    const int col = ch * 64 + c4 * 16 + mm;
    bv[c4] = load_f(bias[mat], col, f);
    #pragma unroll
    for (int kt = 0; kt < KT; ++kt)
      bfrag[kt][c4] = *(const s16x8*)(WT + ((((kt * 4 + quad) << 7) + col) << 3));
  }

  const int wrowbase = blockIdx.x * 256 + wid * 64;

  #pragma unroll
  for (int i = 0; i < 4; ++i) {
    const int rtbase = wrowbase + i * 16;
    const int arow = rtbase + mm;
    s16x8 afrag[KT];
    if (arow < n) {
      if (xf) {
        const float* xp = (const float*)X + (size_t)arow * KD;
        #pragma unroll
        for (int kt = 0; kt < KT; ++kt) {
          const float4* p = (const float4*)(xp + kt * 32 + quad * 8);
          float4 a = p[0], b = p[1];
          s16x8 fr;
          fr[0] = f2bfs(a.x); fr[1] = f2bfs(a.y); fr[2] = f2bfs(a.z); fr[3] = f2bfs(a.w);
          fr[4] = f2bfs(b.x); fr[5] = f2bfs(b.y); fr[6] = f2bfs(b.z); fr[7] = f2bfs(b.w);
          afrag[kt] = fr;
        }
      } else {
        const short* xp = (const short*)X + (size_t)arow * KD;
        #pragma unroll
        for (int kt = 0; kt < KT; ++kt)
          afrag[kt] = *(const s16x8*)(xp + kt * 32 + quad * 8);
      }
    } else {
      #pragma unroll
      for (int kt = 0; kt < KT; ++kt)
        afrag[kt] = (s16x8){0,0,0,0,0,0,0,0};
    }

    f32x4 acc[4];
    #pragma unroll
    for (int c4 = 0; c4 < 4; ++c4) {
      f32x4 av = {bv[c4], bv[c4], bv[c4], bv[c4]};
      acc[c4] = av;
    }
    #pragma unroll
    for (int kt = 0; kt < KT; ++kt) {
      #pragma unroll
      for (int c4 = 0; c4 < 4; ++c4)
        acc[c4] = __builtin_amdgcn_mfma_f32_16x16x32_bf16(afrag[kt], bfrag[kt][c4], acc[c4], 0, 0, 0);
    }
    #pragma unroll
    for (int c4 = 0; c4 < 4; ++c4) {
      const int col = ch * 64 + c4 * 16 + mm;
      #pragma unroll
      for (int r = 0; r < 4; ++r) {
        const int row = rtbase + quad * 4 + r;
        if (row < n)
          ((__hip_bfloat16*)O)[(size_t)row * os + oo + col] = __float2bfloat16(acc[c4][r]);
      }
    }
  }
}

// ---------------- attention v4 ----------------
// 1 wave per dst (4 dsts/block). 4 edge slots x 16 channel-lanes; quad = head.
// No-max softmax (logits tiny), native exp2, DPP quad reduction, interleaved KV
// rows (512B), 1-deep KV prefetch + 2-deep ssrc prefetch.
// H may alias S (in-place per dst row).

__global__ __launch_bounds__(256)
void attn_kernel(const unsigned short* __restrict__ Q, const unsigned short* __restrict__ KV,
                 const unsigned short* S,
                 const int* __restrict__ offs, const int* __restrict__ ssrc,
                 unsigned short* H)
{
  const int dst = blockIdx.x * 4 + (threadIdx.x >> 6);
  if (dst >= N_NODES) return;               // wave-uniform
  const int lane = threadIdx.x & 63;
  const int sub  = lane >> 4;
  const int cl   = lane & 15;

  const float qs = 0.17677669529663687f * 1.4426950408889634f;
  uint4 qw = *(const uint4*)(Q + (size_t)dst * 128 + cl * 8);
  float q[8], a[8];
  #pragma unroll
  for (int i = 0; i < 4; ++i) {
    unsigned w = ((unsigned*)&qw)[i];
    q[2 * i]     = bfbits2f(w & 0xffffu) * qs;
    q[2 * i + 1] = bfhi2f(w) * qs;
    a[2 * i] = 0.f; a[2 * i + 1] = 0.f;
  }
  float s = 0.f;

  const int e0 = offs[dst], e1 = offs[dst + 1];
  const int iters = (e1 - e0 + 3) >> 2;

  if (iters > 0) {
    int e = e0 + sub;
    bool have = (e < e1);
    int src = have ? ssrc[e] : ssrc[e0];
    float ph = have ? 1.f : 0.f;
    int e2 = e + 4;
    bool have2 = (e2 < e1);
    int src2 = have2 ? ssrc[e2] : ssrc[e0];
    float ph2 = have2 ? 1.f : 0.f;

    const unsigned short* kvr = KV + (size_t)src * 256 + cl * 8;
    uint4 kw = *(const uint4*)(kvr);
    uint4 vw = *(const uint4*)(kvr + 128);

    for (int it = 0; it < iters; ++it) {
      uint4 kwn, vwn;
      if (it + 1 < iters) {                 // wave-uniform
        const unsigned short* kvn = KV + (size_t)src2 * 256 + cl * 8;
        kwn = *(const uint4*)(kvn);
        vwn = *(const uint4*)(kvn + 128);
      } else {
        kwn = kw; vwn = vw;
      }
      // prefetch ssrc two iterations ahead
      int e3 = e2 + 4;
      bool have3 = (e3 < e1);
      int src3 = have3 ? ssrc[e3] : ssrc[e0];
      float ph3 = have3 ? 1.f : 0.f;

      float d = 0.f;
      #pragma unroll
      for (int i = 0; i < 4; ++i) {
        unsigned w = ((unsigned*)&kw)[i];
        d += q[2 * i]     * bfbits2f(w & 0xffffu);
        d += q[2 * i + 1] * bfhi2f(w);
      }
      d = quad_reduce_add(d);               // sum over the 4 lanes of this head
      float p = fast_exp2(d) * ph;
      s += p;
      #pragma unroll
      for (int i = 0; i < 4; ++i) {
        unsigned w = ((unsigned*)&vw)[i];
        a[2 * i]     += p * bfbits2f(w & 0xffffu);
        a[2 * i + 1] += p * bfhi2f(w);
      }
      kw = kwn; vw = vwn; ph = ph2;
      src2 = src3; ph2 = ph3; e2 = e3;
    }
  }

  // merge the 4 edge slots (same cl -> same head)
  s += __shfl_xor(s, 16, 64);
  s += __shfl_xor(s, 32, 64);
  #pragma unroll
  for (int i = 0; i < 8; ++i) {
    a[i] += __shfl_xor(a[i], 16, 64);
    a[i] += __shfl_xor(a[i], 32, 64);
  }
  const float inv = (s > 0.f) ? (1.0f / s) : 0.f;

  if (sub == 0) {
    uint4 sw = *(const uint4*)(S + (size_t)dst * 128 + cl * 8);
    uint4 ow;
    #pragma unroll
    for (int i = 0; i < 4; ++i) {
      unsigned w = ((unsigned*)&sw)[i];
      float o0 = fmaxf(a[2 * i] * inv     + bfbits2f(w & 0xffffu), 0.f);
      float o1 = fmaxf(a[2 * i + 1] * inv + bfhi2f(w), 0.f);
      ((unsigned*)&ow)[i] = (unsigned)f2bfu(o0) | ((unsigned)f2bfu(o1) << 16);
    }
    *(uint4*)(H + (size_t)dst * 128 + cl * 8) = ow;
  }
}

// ---------------- pooling + final linear ----------------

__device__ __forceinline__ int lower_bound_b(const void* b, int n, long long val, int i64) {
  int lo = 0, hi = n;
  while (lo < hi) { int mid = (lo + hi) >> 1; if (load_b(b, mid, i64) < val) lo = mid + 1; else hi = mid; }
  return lo;
}

__global__ __launch_bounds__(128)
void pool_partial(const __hip_bfloat16* __restrict__ H, const void* __restrict__ batch,
                  float* __restrict__ pooled, const int* __restrict__ flags)
{
  const int g = blockIdx.x >> 4, p = blockIdx.x & 15, t = threadIdx.x;
  const int i64 = flags[1];
  const int s = lower_bound_b(batch, N_NODES, g, i64);
  const int e = lower_bound_b(batch, N_NODES, g + 1, i64);
  const int len = e - s;
  if (len <= 0) return;
  const int chunk = (len + 15) >> 4;
  const int a = s + p * chunk;
  const int b = min(a + chunk, e);
  if (a >= b) return;
  float sum = 0.f;
  for (int i = a; i < b; ++i) sum += bf2f(H[(size_t)i * 128 + t]);
  atomicAdd(&pooled[g * 128 + t], sum);
}

__global__ __launch_bounds__(128)
void pool_final(const float* __restrict__ pooled, const void* __restrict__ batch,
                const void* __restrict__ Wl, const void* __restrict__ bl,
                void* out, const int* __restrict__ flags)
{
  const int g = blockIdx.x, t = threadIdx.x;
  __shared__ float r0[128], r1[128];
  const int i64 = flags[1], f = flags[0];
  const int s = lower_bound_b(batch, N_NODES, g, i64);
  const int e = lower_bound_b(batch, N_NODES, g + 1, i64);
  const float inv = 1.0f / (float)max(e - s, 1);
  const float pc = pooled[g * 128 + t] * inv;
  r0[t] = pc * load_f(Wl, t * 2 + 0, f);
  r1[t] = pc * load_f(Wl, t * 2 + 1, f);
  __syncthreads();
  for (int o = 64; o > 0; o >>= 1) {
    if (t < o) { r0[t] += r0[t + o]; r1[t] += r1[t + o]; }
    __syncthreads();
  }
  if (t == 0) {
    float o0 = r0[0] + load_f(bl, 0, f);
    float o1 = r1[0] + load_f(bl, 1, f);
    if (f) {
      ((float*)out)[g * 2 + 0] = o0;
      ((float*)out)[g * 2 + 1] = o1;
    } else {
      ((__hip_bfloat16*)out)[g * 2 + 0] = __float2bfloat16(o0);
      ((__hip_bfloat16*)out)[g * 2 + 1] = __float2bfloat16(o1);
    }
  }
}

// ---------------- launch ----------------

extern "C" void kernel_launch(void* const* d_in, const int* in_sizes, int n_in,
                              void* d_out, int out_size, void* d_ws, size_t ws_size,
                              hipStream_t stream) {
  uintptr_t base = (uintptr_t)d_ws;
  auto take = [&](size_t bytes) -> uintptr_t {
    uintptr_t p = base;
    base += (bytes + 255) & ~(size_t)255;
    return p;
  };

  int*   flags  = (int*)take(2 * 4);
  int*   cnt    = (int*)take((size_t)N_NODES * 4);
  int*   tmp    = (int*)take((size_t)N_NODES * 4);
  int*   offs   = (int*)take((size_t)(N_NODES + 1) * 4);
  int*   bsum   = (int*)take((size_t)NB_SCAN * 4);
  int*   ssrc   = (int*)take((size_t)N_EDGES * 4);
  short* Qb     = (short*)take((size_t)N_NODES * 128 * 2);
  short* KVb    = (short*)take((size_t)N_NODES * 256 * 2);  // interleaved [K|V] rows
  short* Sb     = (short*)take((size_t)N_NODES * 128 * 2);  // S / H / layer-2 X (in-place)
  short* wt1q   = (short*)take((size_t)IN_CH * 128 * 2);
  short* wt1k   = (short*)take((size_t)IN_CH * 128 * 2);
  short* wt1v   = (short*)take((size_t)IN_CH * 128 * 2);
  short* wt1s   = (short*)take((size_t)IN_CH * 128 * 2);
  short* wt2q   = (short*)take((size_t)HID_CH * 128 * 2);
  short* wt2k   = (short*)take((size_t)HID_CH * 128 * 2);
  short* wt2v   = (short*)take((size_t)HID_CH * 128 * 2);
  short* wt2s   = (short*)take((size_t)HID_CH * 128 * 2);
  float* pooled = (float*)take((size_t)N_GRAPHS * 128 * 4);

  detect_init<<<NB_SCAN + 1, 256, 0, stream>>>(
      (const unsigned*)d_in[0], (const unsigned*)d_in[1], flags, cnt, tmp, pooled);

  conv_wt<<<(4 * 64 * 128 + 4 * 128 * 128 + 255) / 256, 256, 0, stream>>>(
      d_in[3], d_in[5], d_in[7], d_in[9], d_in[11], d_in[13], d_in[15], d_in[17],
      (__hip_bfloat16*)wt1q, (__hip_bfloat16*)wt1k, (__hip_bfloat16*)wt1v, (__hip_bfloat16*)wt1s,
      (__hip_bfloat16*)wt2q, (__hip_bfloat16*)wt2k, (__hip_bfloat16*)wt2v, (__hip_bfloat16*)wt2s,
      flags);

  count_deg<<<(N_EDGES + 255) / 256, 256, 0, stream>>>(d_in[1], cnt, flags);
  scan1<<<NB_SCAN, 256, 0, stream>>>(cnt, offs, bsum);
  scan2<<<1, 256, 0, stream>>>(bsum, offs);
  scan3<<<NB_SCAN, 256, 0, stream>>>(offs, bsum);
  scatter_edges<<<(N_EDGES + 255) / 256, 256, 0, stream>>>(d_in[1], offs, tmp, ssrc, flags);

  const int rowchunks = (N_NODES + 255) / 256;   // 196
  const int attn_grid = (N_NODES + 3) / 4;

  // ---- layer 1: X = raw x (no aliasing) -> all 4 mats in one dispatch ----
  gemm_v3<IN_CH><<<dim3(rowchunks, 8), 256, 0, stream>>>(
      d_in[0], wt1q, wt1k, wt1v, wt1s,
      d_in[4], d_in[6], d_in[8], d_in[10],
      Qb, KVb, Sb, flags, 1, 0, N_NODES);
  attn_kernel<<<attn_grid, 256, 0, stream>>>(
      (const unsigned short*)Qb, (const unsigned short*)KVb,
      (const unsigned short*)Sb, offs, ssrc, (unsigned short*)Sb);

  // ---- layer 2: X = Sb. QKV first; S separately (in-place per-row) ----
  gemm_v3<HID_CH><<<dim3(rowchunks, 6), 256, 0, stream>>>(
      Sb, wt2q, wt2k, wt2v, wt2s,
      d_in[12], d_in[14], d_in[16], d_in[18],
      Qb, KVb, Sb, flags, 0, 0, N_NODES);
  gemm_v3<HID_CH><<<dim3(rowchunks, 2), 256, 0, stream>>>(
      Sb, wt2q, wt2k, wt2v, wt2s,
      d_in[12], d_in[14], d_in[16], d_in[18],
      Qb, KVb, Sb, flags, 0, 3, N_NODES);
  attn_kernel<<<attn_grid, 256, 0, stream>>>(
      (const unsigned short*)Qb, (const unsigned short*)KVb,
      (const unsigned short*)Sb, offs, ssrc, (unsigned short*)Sb);

  // ---- pool + linear ----
  pool_partial<<<N_GRAPHS * 16, 128, 0, stream>>>(
      (const __hip_bfloat16*)Sb, d_in[2], pooled, flags);
  pool_final<<<N_GRAPHS, 128, 0, stream>>>(pooled, d_in[2], d_in[19], d_in[20], d_out, flags);
}